// Round 2
// baseline (13379.811 us; speedup 1.0000x reference)
//
#include <hip/hip_runtime.h>
#include <stdint.h>

// LSTM  B=128, S=256, I=1024, H=1024
// Phase 1: gates_x = x @ Wx^T + b   (parallel GEMM, bf16 MFMA, m97-style)
// Phase 2: persistent per-chunk kernel, 32 steps/launch. 4 independent m-groups
//          (m-tile 32) x 64 h-blocks = 256 blocks = 1/CU (144KB LDS). Wh slice
//          resident in LDS across steps; c-state in registers; 64-block group
//          barrier (device-scope atomics + __threadfence) between steps.
//
// Workspace layout (bytes):
//   Xc    bf16 [S*B][I]      67,108,864   @ 0           (row m = s*128 + b)
//   Whp   bf16 [4H][H]        8,388,608   @ 67,108,864  (n = gate*1024+h; f,i,g,o)
//   Wxp   bf16 [4H][I]        8,388,608   @ 75,497,472
//   biasp f32  [4H]              16,384   @ 83,886,080
//   h2    bf16 2*[128][1024]    524,288   @ 83,902,464  (ping-pong)
//   cws   f32  [128][1024]      524,288   @ 84,426,752
//   cnt   u32  [4][256]           4,096   @ 84,951,040  (barrier counters)
//   gx    bf16 [4096][4096]  33,554,432   @ 84,955,136  (one 32-step chunk)
// total 118,509,568

typedef unsigned short u16;
typedef unsigned int u32;
typedef __bf16 bf16x8 __attribute__((ext_vector_type(8)));
typedef float f32x4 __attribute__((ext_vector_type(4)));

__device__ __forceinline__ u16 f2bf(float f) {
  u32 u = __builtin_bit_cast(u32, f);
  u = (u + 0x7fffu + ((u >> 16) & 1u)) >> 16;
  return (u16)u;
}
__device__ __forceinline__ float bf2f(u16 s) {
  u32 u = ((u32)s) << 16;
  return __builtin_bit_cast(float, u);
}
__device__ __forceinline__ u32 pack2bf(float a, float b) {
  return (u32)f2bf(a) | ((u32)f2bf(b) << 16);
}

__device__ __forceinline__ void gl2lds16(const void* gptr, void* lptr) {
  __builtin_amdgcn_global_load_lds(
      (__attribute__((address_space(1))) void*)(uintptr_t)gptr,
      (__attribute__((address_space(3))) void*)(uintptr_t)lptr, 16, 0, 0);
}

__device__ __forceinline__ float sigm(float x) { return 1.f / (1.f + __expf(-x)); }
__device__ __forceinline__ float tanh_f(float x) { return 2.f / (1.f + __expf(-2.f * x)) - 1.f; }

// ---------------- pack / convert kernels ----------------

__global__ __launch_bounds__(256) void convert_x(const float* __restrict__ x, u16* __restrict__ Xc) {
  int t = blockIdx.x * 256 + threadIdx.x;
  int i8 = t & 127;
  int s = (t >> 7) & 255;
  int b = t >> 15;
  const float4* src = (const float4*)(x + (((b << 8) + s) << 10) + (i8 << 3));
  float4 a = src[0], c = src[1];
  uint4 o;
  o.x = pack2bf(a.x, a.y); o.y = pack2bf(a.z, a.w);
  o.z = pack2bf(c.x, c.y); o.w = pack2bf(c.z, c.w);
  *(uint4*)(Xc + (((s << 7) + b) << 10) + (i8 << 3)) = o;
}

__global__ __launch_bounds__(256) void pack_w(const float* __restrict__ Wf, const float* __restrict__ Wi,
                                              const float* __restrict__ Wc, const float* __restrict__ Wo,
                                              u16* __restrict__ Whp, u16* __restrict__ Wxp) {
  int t = blockIdx.x * 256 + threadIdx.x;
  int k8 = t & 127, n = t >> 7;
  int g = n >> 10, h = n & 1023;
  const float* W = (g == 0) ? Wf : (g == 1) ? Wi : (g == 2) ? Wc : Wo;
  const float4* ph = (const float4*)(W + h * 2048 + (k8 << 3));
  float4 a = ph[0], b = ph[1];
  uint4 oh;
  oh.x = pack2bf(a.x, a.y); oh.y = pack2bf(a.z, a.w);
  oh.z = pack2bf(b.x, b.y); oh.w = pack2bf(b.z, b.w);
  *(uint4*)(Whp + n * 1024 + (k8 << 3)) = oh;
  const float4* px = (const float4*)(W + h * 2048 + 1024 + (k8 << 3));
  float4 c = px[0], d = px[1];
  uint4 ox;
  ox.x = pack2bf(c.x, c.y); ox.y = pack2bf(c.z, c.w);
  ox.z = pack2bf(d.x, d.y); ox.w = pack2bf(d.z, d.w);
  *(uint4*)(Wxp + n * 1024 + (k8 << 3)) = ox;
}

__global__ __launch_bounds__(256) void pack_b(const float* __restrict__ bf_, const float* __restrict__ bi,
                                              const float* __restrict__ bc, const float* __restrict__ bo,
                                              float* __restrict__ biasp) {
  int n = blockIdx.x * 256 + threadIdx.x;
  int g = n >> 10, h = n & 1023;
  const float* b = (g == 0) ? bf_ : (g == 1) ? bi : (g == 2) ? bc : bo;
  biasp[n] = b[h];
}

// ---------------- phase 1 GEMM: gx = Xc @ Wxp^T + bias (unchanged, verified) ----------------
__global__ __launch_bounds__(256) void gemm_x(const u16* __restrict__ A,
                                              const u16* __restrict__ Bw,
                                              const float* __restrict__ bias,
                                              u16* __restrict__ gx,
                                              int m_base) {
  __shared__ __align__(16) u16 lds_a[128 * 64];
  __shared__ __align__(16) u16 lds_b[128 * 64];
  const int tid = threadIdx.x;
  const int lane = tid & 63, q = lane >> 4, cl = lane & 15;
  const int w = tid >> 6, wm = w & 1, wn = w >> 1;
  const int m0 = m_base + blockIdx.y * 128;
  const int n0 = blockIdx.x * 128;
  f32x4 acc[4][4] = {};

  for (int it = 0; it < 16; ++it) {
    const int k0 = it * 64;
#pragma unroll
    for (int itn = 0; itn < 4; ++itn) {
      int j = itn * 256 + tid;
      int row = j >> 3, c8s = (j & 7) ^ (row & 7);
      gl2lds16(A + (m0 + row) * 1024 + k0 + c8s * 8, &lds_a[j * 8]);
    }
#pragma unroll
    for (int itn = 0; itn < 4; ++itn) {
      int j = itn * 256 + tid;
      int row = j >> 3, c8s = (j & 7) ^ (row & 7);
      gl2lds16(Bw + (n0 + row) * 1024 + k0 + c8s * 8, &lds_b[j * 8]);
    }
    asm volatile("s_waitcnt vmcnt(0)" ::: "memory");
    __syncthreads();
#pragma unroll
    for (int kk = 0; kk < 2; ++kk) {
      bf16x8 af[4], bfr[4];
#pragma unroll
      for (int mt = 0; mt < 4; ++mt) {
        int row = wm * 64 + mt * 16 + cl;
        int c8 = (kk * 4 + q) ^ (row & 7);
        af[mt] = *(const bf16x8*)&lds_a[row * 64 + c8 * 8];
      }
#pragma unroll
      for (int nt = 0; nt < 4; ++nt) {
        int row = wn * 64 + nt * 16 + cl;
        int c8 = (kk * 4 + q) ^ (row & 7);
        bfr[nt] = *(const bf16x8*)&lds_b[row * 64 + c8 * 8];
      }
#pragma unroll
      for (int mt = 0; mt < 4; ++mt)
#pragma unroll
        for (int nt = 0; nt < 4; ++nt)
          acc[mt][nt] = __builtin_amdgcn_mfma_f32_16x16x32_bf16(af[mt], bfr[nt], acc[mt][nt], 0, 0, 0);
    }
    __syncthreads();
  }
#pragma unroll
  for (int nt = 0; nt < 4; ++nt) {
    int n = n0 + wn * 64 + nt * 16 + cl;
    float bv = bias[n];
#pragma unroll
    for (int mt = 0; mt < 4; ++mt) {
#pragma unroll
      for (int r = 0; r < 4; ++r) {
        int m_loc = blockIdx.y * 128 + wm * 64 + mt * 16 + q * 4 + r;
        gx[m_loc * 4096 + n] = f2bf(acc[mt][nt][r] + bv);
      }
    }
  }
}

// ---------------- phase 2: persistent chunk kernel (32 steps) ----------------
// grid (64, 4): bx -> h0 = 16*bx (16 h cols x 4 gates = 64 n rows), by -> m-group (m0 = 32*by).
// LDS: Whs [64][1024] bf16 resident (128KB) + Aws dbuf [2][32][128] (16KB); pre aliases Aws.
__global__ __launch_bounds__(256) void lstm_chunk(const u16* __restrict__ Whp,
                                                  const u16* __restrict__ gx,
                                                  u16* __restrict__ h2,      // 2 x [128][1024]
                                                  float* __restrict__ cws,   // [128][1024]
                                                  u32* __restrict__ counters,
                                                  float* __restrict__ out,   // [128][256][1024]
                                                  int chunk) {
  extern __shared__ __align__(16) char smem[];
  u16* Whs = (u16*)smem;                 // [64][1024], k-chunk swizzled per row
  u16* Aws = (u16*)(smem + 131072);      // [2][32][128], swizzled
  float* pre = (float*)(smem + 131072);  // [64][33] f32, aliases Aws (disjoint lifetime)

  const int tid = threadIdx.x;
  const int lane = tid & 63, q = lane >> 4, cl = lane & 15;
  const int w = tid >> 6;
  const int kh = w >> 1;   // k-parity this wave computes
  const int np = w & 1;    // n-subtile pair
  const int h0 = blockIdx.x * 16;
  const int m0 = blockIdx.y * 32;
  const int g = blockIdx.y;

  // resident Wh slice: 64 rows (16 h x 4 gates) x 1024 k, source-swizzled
#pragma unroll
  for (int it = 0; it < 32; ++it) {
    int j = it * 256 + tid;     // 16B-chunk id, 0..8191
    int row = j >> 7;           // 0..63
    int cpos = j & 127;
    int csrc = cpos ^ (row & 7);
    int ng = ((row >> 4) << 10) + h0 + (row & 15);
    gl2lds16(Whp + ng * 1024 + csrc * 8, Whs + j * 8);
  }

  // c-state in registers (2 cells/thread): lin = tid, tid+256 -> m_loc = lin>>4, hl = lin&15
  const int mA = m0 + (tid >> 4), mB = mA + 16;
  const int hg = h0 + (tid & 15);
  float c0 = cws[mA * 1024 + hg];
  float c1 = cws[mB * 1024 + hg];

  for (int t = 0; t < 32; ++t) {
    const int s = chunk * 32 + t;
    const u16* hin = h2 + (s & 1) * 131072;
    u16* hout = h2 + ((s + 1) & 1) * 131072;

    f32x4 acc[2][2] = {};  // [msub][nsub-rel]

    // stage A k-slice sl (128 k wide) into Aws[sl&1]
    auto stageA = [&](int sl) {
      const int kb = sl * 128;
#pragma unroll
      for (int itn = 0; itn < 2; ++itn) {
        int j = itn * 256 + tid;  // 0..511
        int row = j >> 4;         // 0..31
        int cpos = j & 15;
        int csrc = cpos ^ (row & 7);
        gl2lds16(hin + (m0 + row) * 1024 + kb + csrc * 8, Aws + ((sl & 1) << 12) + j * 8);
      }
    };

    stageA(0);
    for (int sl = 0; sl < 8; ++sl) {
      asm volatile("s_waitcnt vmcnt(0)" ::: "memory");
      __syncthreads();
      if (sl < 7) stageA(sl + 1);
      if ((sl & 1) == kh) {
        const u16* Ab = Aws + ((sl & 1) << 12);
#pragma unroll
        for (int ks = 0; ks < 4; ++ks) {
          bf16x8 af[2], bfrag[2];
#pragma unroll
          for (int ms = 0; ms < 2; ++ms) {
            int row = ms * 16 + cl;
            int pos = ((ks << 2) + q) ^ (row & 7);
            af[ms] = *(const bf16x8*)(Ab + row * 128 + pos * 8);
          }
#pragma unroll
          for (int ns = 0; ns < 2; ++ns) {
            int nrow = ((np << 1) + ns) * 16 + cl;
            int gch = (((sl << 2) + ks) << 2) + q;  // global k-chunk 0..127
            int pos = gch ^ (nrow & 7);
            bfrag[ns] = *(const bf16x8*)(Whs + nrow * 1024 + pos * 8);
          }
#pragma unroll
          for (int ms = 0; ms < 2; ++ms)
#pragma unroll
            for (int ns = 0; ns < 2; ++ns)
              acc[ms][ns] = __builtin_amdgcn_mfma_f32_16x16x32_bf16(af[ms], bfrag[ns], acc[ms][ns], 0, 0, 0);
        }
      }
    }

    // reduce k-halves into pre[n][m] (Aws dead from here to end of step)
    __syncthreads();
    if (kh == 1) {
#pragma unroll
      for (int ms = 0; ms < 2; ++ms)
#pragma unroll
        for (int ns = 0; ns < 2; ++ns) {
          int n_loc = ((np << 1) + ns) * 16 + cl;
#pragma unroll
          for (int r = 0; r < 4; ++r)
            pre[n_loc * 33 + ms * 16 + q * 4 + r] = acc[ms][ns][r];
        }
    }
    __syncthreads();
    if (kh == 0) {
#pragma unroll
      for (int ms = 0; ms < 2; ++ms)
#pragma unroll
        for (int ns = 0; ns < 2; ++ns) {
          int n_loc = ((np << 1) + ns) * 16 + cl;
#pragma unroll
          for (int r = 0; r < 4; ++r)
            pre[n_loc * 33 + ms * 16 + q * 4 + r] += acc[ms][ns][r];
        }
    }
    __syncthreads();

    // cell update: 2 cells/thread, gates lane-local via pre[gate*16+hl][m_loc]
    const int hl = tid & 15;
#pragma unroll
    for (int e = 0; e < 2; ++e) {
      int m_loc = (tid >> 4) + e * 16;
      int m = m0 + m_loc;
      const u16* gp = gx + (size_t)(((s & 31) << 7) + m) * 4096;
      float pf = pre[(hl) * 33 + m_loc]      + bf2f(gp[hg]);
      float pi = pre[(16 + hl) * 33 + m_loc] + bf2f(gp[1024 + hg]);
      float pg = pre[(32 + hl) * 33 + m_loc] + bf2f(gp[2048 + hg]);
      float po = pre[(48 + hl) * 33 + m_loc] + bf2f(gp[3072 + hg]);
      float fg = sigm(pf), ig = sigm(pi), gg = tanh_f(pg), og = sigm(po);
      float& cr = e ? c1 : c0;
      cr = cr * fg + ig * gg;
      float hn = tanh_f(cr) * og;
      hout[m * 1024 + hg] = f2bf(hn);
      out[((size_t)m * 256 + s) * 1024 + hg] = hn;
    }

    // group barrier (64 blocks sharing m-group g); skip after last step of chunk
    if (t != 31) {
      __threadfence();   // release: wbl2 -> h writes visible across XCDs
      __syncthreads();
      if (tid == 0) {
        u32* cnt = counters + (g << 8) + s;
        __hip_atomic_fetch_add(cnt, 1u, __ATOMIC_RELEASE, __HIP_MEMORY_SCOPE_AGENT);
        while (__hip_atomic_load(cnt, __ATOMIC_ACQUIRE, __HIP_MEMORY_SCOPE_AGENT) < 64u)
          __builtin_amdgcn_s_sleep(1);
      }
      __syncthreads();
      __threadfence();   // acquire: inv -> don't read stale h from local L1/L2
    }
  }

  cws[mA * 1024 + hg] = c0;
  cws[mB * 1024 + hg] = c1;
}

// ---------------- launch ----------------

extern "C" void kernel_launch(void* const* d_in, const int* in_sizes, int n_in,
                              void* d_out, int out_size, void* d_ws, size_t ws_size,
                              hipStream_t stream) {
  const float* x   = (const float*)d_in[0];
  const float* Wf  = (const float*)d_in[1];
  const float* bf_ = (const float*)d_in[2];
  const float* Wi  = (const float*)d_in[3];
  const float* bi  = (const float*)d_in[4];
  const float* Wc  = (const float*)d_in[5];
  const float* bc  = (const float*)d_in[6];
  const float* Wo  = (const float*)d_in[7];
  const float* bo  = (const float*)d_in[8];
  float* out = (float*)d_out;
  char* ws = (char*)d_ws;

  const size_t NEEDED = 118509568;
  if (ws_size < NEEDED) return;

  u16*   Xc    = (u16*)(ws);
  u16*   Whp   = (u16*)(ws + 67108864);
  u16*   Wxp   = (u16*)(ws + 75497472);
  float* biasp = (float*)(ws + 83886080);
  u16*   h2    = (u16*)(ws + 83902464);
  float* cws   = (float*)(ws + 84426752);
  u32*   cnt   = (u32*)(ws + 84951040);
  u16*   gx    = (u16*)(ws + 84955136);

  hipFuncSetAttribute((const void*)lstm_chunk,
                      hipFuncAttributeMaxDynamicSharedMemorySize, 147456);

  // zero h ping-pong + c-state + barrier counters
  hipMemsetAsync(ws + 83902464, 0, 1052672, stream);
  convert_x<<<16384, 256, 0, stream>>>(x, Xc);
  pack_w<<<2048, 256, 0, stream>>>(Wf, Wi, Wc, Wo, Whp, Wxp);
  pack_b<<<16, 256, 0, stream>>>(bf_, bi, bc, bo, biasp);

  for (int c = 0; c < 8; ++c) {
    gemm_x<<<dim3(32, 32), 256, 0, stream>>>(Xc, Wxp, biasp, gx, c * 4096);
    lstm_chunk<<<dim3(64, 4), 256, 147456, stream>>>(Whp, gx, h2, cws, cnt, out, c);
  }
}